// Round 7
// baseline (1408.980 us; speedup 1.0000x reference)
//
#include <hip/hip_runtime.h>
#include <hip/hip_bf16.h>
#include <stdint.h>

#define B_    128
#define F_    4
#define V_    2048
#define D_    4096
#define DW    64      // D/64 bit-words per (b,f) row
#define VW    32      // V/64 bit-words per d column
#define ITERS 20
#define NKT   8       // K tiles of 256 over V=2048
#define NBS   66      // padded LDS stride (u64) for nb/eb rows

typedef _Float16 half8 __attribute__((ext_vector_type(8)));
typedef float   floatx4 __attribute__((ext_vector_type(4)));

__device__ __forceinline__ void pack16(const float* __restrict__ x, int t,
                                       uint16_t* __restrict__ dst) {
    const float4* p = (const float4*)(x + (size_t)t * 16);
    unsigned m = 0;
    #pragma unroll
    for (int j = 0; j < 4; ++j) {
        float4 v = p[j];
        m |= (v.x < 0.0f ? 1u : 0u) << (4 * j + 0);
        m |= (v.y < 0.0f ? 1u : 0u) << (4 * j + 1);
        m |= (v.z < 0.0f ? 1u : 0u) << (4 * j + 2);
        m |= (v.w < 0.0f ? 1u : 0u) << (4 * j + 3);
    }
    dst[t] = (uint16_t)m;
}

// ------------------------------------------------------------------
// Prep 1: pack cb/inite/inputs sign bits; zero flags & keys.
// ------------------------------------------------------------------
__global__ __launch_bounds__(256) void k_packall(
        const float* __restrict__ cb, const float* __restrict__ inite,
        const float* __restrict__ inputs,
        uint16_t* __restrict__ cbb, uint16_t* __restrict__ e16,
        uint16_t* __restrict__ i16, int* __restrict__ flags,
        int* __restrict__ keys) {
    int gtid = blockIdx.x * 256 + threadIdx.x, gsz = gridDim.x * 256;
    for (int t = gtid; t < F_ * V_ * D_ / 16; t += gsz) pack16(cb, t, cbb);
    for (int t = gtid; t < B_ * F_ * D_ / 16; t += gsz) pack16(inite, t, e16);
    for (int t = gtid; t < B_ * D_ / 16; t += gsz) pack16(inputs, t, i16);
    if (gtid < ITERS) flags[gtid] = 0;
    if (gtid >= 32 && gtid < 32 + B_ * F_) keys[gtid - 32] = 0;
}

// ------------------------------------------------------------------
// Prep 2: transpose cb bits -> cbT[f][d][vwords]; nbc = in^e0^e1^e2^e3.
// ------------------------------------------------------------------
__global__ __launch_bounds__(256) void k_prep(
        const uint64_t* __restrict__ cb_bits, uint64_t* __restrict__ cbT,
        const uint64_t* __restrict__ in_bits, const uint64_t* __restrict__ est_bits,
        uint64_t* __restrict__ nbc) {
    int u = blockIdx.x, tid = threadIdx.x;
    int lane = tid & 63;
    int vw = u & 31, dwg = (u >> 5) & 15, f = u >> 9;
    int dw = dwg * 4 + (tid >> 6);
    uint64_t w = cb_bits[((size_t)f * V_ + vw * 64 + lane) * DW + dw];
    uint64_t r = 0;
    for (int d2 = 0; d2 < 64; ++d2) {
        uint64_t m = __ballot((unsigned)((w >> d2) & 1));
        if (lane == d2) r = m;
    }
    cbT[((size_t)f * D_ + dw * 64 + lane) * VW + vw] = r;

    int gtid = u * 256 + tid;
    if (gtid < B_ * DW) {
        int b = gtid >> 6, ww = gtid & 63;
        const uint64_t* e = est_bits + (size_t)b * F_ * DW;
        nbc[gtid] = in_bits[gtid] ^ e[ww] ^ e[DW + ww] ^ e[2 * DW + ww] ^ e[3 * DW + ww];
    }
}

// ------------------------------------------------------------------
// sim v3: register-blocked 4v x 4b.  Block = 128 thr covers 64 v x 32 b.
// nb staged once to padded LDS; grid (vt=32, bt=4, f=4) = 512 blocks.
// ------------------------------------------------------------------
__global__ __launch_bounds__(128, 4) void k_sim(
        const uint64_t* __restrict__ cb_bits,
        const uint64_t* __restrict__ nbc,
        const uint64_t* __restrict__ est_bits,
        _Float16* __restrict__ simf,
        const int* __restrict__ flags, int iter) {
    if (iter > 0 && flags[iter - 1] == 0) return;
    int vt = blockIdx.x, bt = blockIdx.y, f = blockIdx.z;
    int tid = threadIdx.x;
    __shared__ __align__(16) uint64_t nb[32 * NBS];
    #pragma unroll
    for (int j = 0; j < 16; ++j) {
        int idx = j * 128 + tid;               // 2048 = 32 b x 64 w
        int bl = idx >> 6, w = idx & 63;
        int b = bt * 32 + bl;
        nb[bl * NBS + w] = nbc[(size_t)b * DW + w]
                         ^ est_bits[((size_t)b * F_ + f) * DW + w];
    }
    __syncthreads();
    int vg = tid >> 3, bg = tid & 7;
    int v0 = vt * 64 + vg * 4;
    const uint64_t* cb0 = cb_bits + ((size_t)f * V_ + v0) * DW;
    int acc[4][4] = {};
    #pragma unroll 4
    for (int s = 0; s < 32; ++s) {
        ulonglong2 c[4], n[4];
        #pragma unroll
        for (int vi = 0; vi < 4; ++vi)
            c[vi] = *(const ulonglong2*)&cb0[(size_t)vi * DW + 2 * s];
        #pragma unroll
        for (int bj = 0; bj < 4; ++bj)
            n[bj] = *(const ulonglong2*)&nb[(bg * 4 + bj) * NBS + 2 * s];
        #pragma unroll
        for (int vi = 0; vi < 4; ++vi)
            #pragma unroll
            for (int bj = 0; bj < 4; ++bj)
                acc[vi][bj] += __popcll(c[vi].x ^ n[bj].x)
                             + __popcll(c[vi].y ^ n[bj].y);
    }
    #pragma unroll
    for (int bj = 0; bj < 4; ++bj) {
        int b = bt * 32 + bg * 4 + bj;
        union { _Float16 h[4]; uint64_t u; } o;
        #pragma unroll
        for (int vi = 0; vi < 4; ++vi)
            o.h[vi] = (_Float16)(2048 - acc[vi][bj]);   // exact, |.|<=2048
        *(uint64_t*)&simf[((size_t)f * B_ + b) * V_ + v0] = o.u;
    }
}

// ------------------------------------------------------------------
// gemm v3: est = sign(sim @ cb^T).  BM=64 BN=64 BK=2048, NO A-LDS:
// A fragments load directly from global (immediate-offset b128),
// K-loop is barrier-free.  grid (nt=64, mt=2, f=4) = 512 blocks.
// ------------------------------------------------------------------
__global__ __launch_bounds__(256, 2) void k_gemm(
        const _Float16* __restrict__ simf,
        const uint64_t* __restrict__ cbT,
        uint64_t* __restrict__ est_bits,
        uint64_t* __restrict__ nbc,
        int* __restrict__ flags, int iter) {
    if (iter > 0 && flags[iter - 1] == 0) return;
    int nt = blockIdx.x, mt = blockIdx.y, f = blockIdx.z;
    int m0 = mt * 64;
    int tid = threadIdx.x;
    int lane = tid & 63, wave = tid >> 6;
    int lrow = lane & 15, lq = lane >> 4;
    int wm = wave & 1, wn = wave >> 1;

    __shared__ __align__(16) uint64_t Bb[64 * VW];        // 16 KB bit panel
    __shared__ __align__(16) unsigned char S[64 * 64];    // 4 KB sign bytes
    __shared__ int bd;
    if (tid == 0) bd = 0;

    // stage B bit-panel (swizzled 16B chunks), as verified in R2/R6
    const uint64_t* bsrc = cbT + ((size_t)f * D_ + nt * 64) * VW;
    #pragma unroll
    for (int p = 0; p < 4; ++p) {
        int chunk = p * 256 + tid;
        int dloc = chunk >> 4, cw = chunk & 15;
        ulonglong2 val = *(const ulonglong2*)&bsrc[dloc * VW + cw * 2];
        *(ulonglong2*)&Bb[dloc * VW + ((cw ^ (dloc & 15)) * 2)] = val;
    }
    __syncthreads();

    // A bases: one pointer per m-fragment; all (kt,ks) offsets are imm
    const _Float16* Abase[2];
    #pragma unroll
    for (int mt2 = 0; mt2 < 2; ++mt2) {
        int m = m0 + wm * 32 + mt2 * 16 + lrow;
        Abase[mt2] = simf + ((size_t)f * B_ + m) * V_ + lq * 8;
    }

    floatx4 acc[2][2] = {};
    #pragma unroll 1
    for (int kt = 0; kt < NKT; ++kt) {
        uint64_t bwv[2][4];
        #pragma unroll
        for (int nt2 = 0; nt2 < 2; ++nt2) {
            int dloc = wn * 32 + nt2 * 16 + lrow;
            #pragma unroll
            for (int cc = 0; cc < 2; ++cc) {
                ulonglong2 t2 = *(const ulonglong2*)&Bb[dloc * VW + (((kt * 2 + cc) ^ (dloc & 15)) * 2)];
                bwv[nt2][cc * 2] = t2.x; bwv[nt2][cc * 2 + 1] = t2.y;
            }
        }
        #pragma unroll
        for (int ks = 0; ks < 8; ++ks) {
            half8 af[2];
            #pragma unroll
            for (int mt2 = 0; mt2 < 2; ++mt2)
                af[mt2] = *(const half8*)&Abase[mt2][kt * 256 + ks * 32];
            half8 bfrag[2];
            #pragma unroll
            for (int nt2 = 0; nt2 < 2; ++nt2) {
                uint32_t byte = (uint32_t)(bwv[nt2][ks >> 1] >> (((ks & 1) * 4 + lq) * 8)) & 0xFFu;
                union { uint32_t u[4]; half8 h; } bu;
                #pragma unroll
                for (int i = 0; i < 4; ++i)
                    bu.u[i] = 0x3C003C00u ^ ((((byte >> (2 * i)) & 3u) * 0x40008000u) & 0x80008000u);
                bfrag[nt2] = bu.h;
            }
            #pragma unroll
            for (int mt2 = 0; mt2 < 2; ++mt2)
                #pragma unroll
                for (int nt2 = 0; nt2 < 2; ++nt2)
                    acc[mt2][nt2] = __builtin_amdgcn_mfma_f32_16x16x32_f16(
                        af[mt2], bfrag[nt2], acc[mt2][nt2], 0, 0, 0);
        }
    }

    // epilogue: hardsign -> S bytes -> u64 word per b-row; update nbc
    #pragma unroll
    for (int mt2 = 0; mt2 < 2; ++mt2)
        #pragma unroll
        for (int nt2 = 0; nt2 < 2; ++nt2)
            #pragma unroll
            for (int r = 0; r < 4; ++r) {
                int row = wm * 32 + mt2 * 16 + lq * 4 + r;   // C/D row = quad*4+reg
                int col = wn * 32 + nt2 * 16 + lrow;         // col = lane&15
                S[row * 64 + col] = (acc[mt2][nt2][r] < 0.0f) ? 1 : 0;  // sign(0)=+1
            }
    __syncthreads();
    if (tid < 64) {
        const uint64_t* Sw = (const uint64_t*)S;
        uint64_t m = 0;
        #pragma unroll
        for (int j = 0; j < 8; ++j) {
            uint64_t w = Sw[tid * 8 + j];
            m |= ((w * 0x0102040810204080ull) >> 56) << (8 * j);
        }
        int b = m0 + tid;
        size_t widx = ((size_t)b * F_ + f) * DW + nt;
        uint64_t old = est_bits[widx];
        if (old != m) {
            est_bits[widx] = m;
            atomicXor((unsigned long long*)&nbc[(size_t)b * DW + nt],
                      (unsigned long long)(old ^ m));
            atomicOr(&bd, 1);
        }
    }
    __syncthreads();
    if (tid == 0 && bd) atomicOr(&flags[iter], 1);
}

// ------------------------------------------------------------------
// argmax on the sim-v3 skeleton: key=(|2048-pc|<<11)|(2047-v).
// grid (vt=32, bt=4, f=4), 128 thr, 4v x 4b per thread.
// ------------------------------------------------------------------
__global__ __launch_bounds__(128) void k_argmax(
        const uint64_t* __restrict__ cb_bits,
        const uint64_t* __restrict__ est_bits,
        int* __restrict__ keys) {
    int vt = blockIdx.x, bt = blockIdx.y, f = blockIdx.z;
    int tid = threadIdx.x;
    __shared__ __align__(16) uint64_t eb[32 * NBS];
    __shared__ int lkey[32];
    #pragma unroll
    for (int j = 0; j < 16; ++j) {
        int idx = j * 128 + tid;
        int bl = idx >> 6, w = idx & 63;
        eb[bl * NBS + w] = est_bits[((size_t)(bt * 32 + bl) * F_ + f) * DW + w];
    }
    if (tid < 32) lkey[tid] = 0;
    __syncthreads();
    int vg = tid >> 3, bg = tid & 7;
    int v0 = vt * 64 + vg * 4;
    const uint64_t* cb0 = cb_bits + ((size_t)f * V_ + v0) * DW;
    int acc[4][4] = {};
    #pragma unroll 4
    for (int s = 0; s < 32; ++s) {
        ulonglong2 c[4], n[4];
        #pragma unroll
        for (int vi = 0; vi < 4; ++vi)
            c[vi] = *(const ulonglong2*)&cb0[(size_t)vi * DW + 2 * s];
        #pragma unroll
        for (int bj = 0; bj < 4; ++bj)
            n[bj] = *(const ulonglong2*)&eb[(bg * 4 + bj) * NBS + 2 * s];
        #pragma unroll
        for (int vi = 0; vi < 4; ++vi)
            #pragma unroll
            for (int bj = 0; bj < 4; ++bj)
                acc[vi][bj] += __popcll(c[vi].x ^ n[bj].x)
                             + __popcll(c[vi].y ^ n[bj].y);
    }
    #pragma unroll
    for (int bj = 0; bj < 4; ++bj) {
        int best = 0;
        #pragma unroll
        for (int vi = 0; vi < 4; ++vi) {
            int m = 2048 - acc[vi][bj]; if (m < 0) m = -m;
            int k = (m << 11) | (2047 - (v0 + vi));
            if (k > best) best = k;
        }
        atomicMax(&lkey[bg * 4 + bj], best);
    }
    __syncthreads();
    if (tid < 32)
        atomicMax(&keys[(size_t)(bt * 32 + tid) * F_ + f], lkey[tid]);
}

__global__ void k_final(const int* __restrict__ keys, const int* __restrict__ flags,
                        int* __restrict__ out) {
    int tid = blockIdx.x * blockDim.x + threadIdx.x;
    if (tid < B_ * F_) out[tid] = 2047 - (keys[tid] & 0x7FF);
    if (tid == 0) {
        int k = ITERS - 1;
        for (int i = 0; i < ITERS; ++i) if (flags[i] == 0) { k = i; break; }
        out[B_ * F_] = k;
    }
}

// ------------------------------------------------------------------
extern "C" void kernel_launch(void* const* d_in, const int* in_sizes, int n_in,
                              void* d_out, int out_size, void* d_ws, size_t ws_size,
                              hipStream_t stream) {
    const float* inputs = (const float*)d_in[0];   // (B, D)
    const float* inite  = (const float*)d_in[1];   // (B, F, D)
    const float* cb     = (const float*)d_in[2];   // (F, V, D)
    int* out = (int*)d_out;                        // 512 outcome + 1 k

    char* ws = (char*)d_ws;
    uint64_t* cb_bits  = (uint64_t*)ws;  ws += (size_t)F_ * V_ * DW * 8;   // 4 MiB
    uint64_t* cbT_bits = (uint64_t*)ws;  ws += (size_t)F_ * D_ * VW * 8;   // 4 MiB
    uint64_t* est_bits = (uint64_t*)ws;  ws += (size_t)B_ * F_ * DW * 8;   // 256 KiB
    uint64_t* in_bits  = (uint64_t*)ws;  ws += (size_t)B_ * DW * 8;        // 64 KiB
    uint64_t* nbc      = (uint64_t*)ws;  ws += (size_t)B_ * DW * 8;        // 64 KiB
    _Float16* simf     = (_Float16*)ws;  ws += (size_t)F_ * B_ * V_ * 2;   // 2 MiB
    int*      flags    = (int*)ws;       ws += 32 * 4;
    int*      keys     = (int*)ws;       ws += B_ * F_ * 4;

    k_packall<<<2048, 256, 0, stream>>>(cb, inite, inputs,
        (uint16_t*)cb_bits, (uint16_t*)est_bits, (uint16_t*)in_bits, flags, keys);
    k_prep<<<2048, 256, 0, stream>>>(cb_bits, cbT_bits, in_bits, est_bits, nbc);

    for (int i = 0; i < ITERS; ++i) {
        k_sim<<<dim3(32, 4, 4), 128, 0, stream>>>(cb_bits, nbc, est_bits, simf, flags, i);
        k_gemm<<<dim3(64, 2, 4), 256, 0, stream>>>(simf, cbT_bits, est_bits, nbc, flags, i);
    }
    k_argmax<<<dim3(32, 4, 4), 128, 0, stream>>>(cb_bits, est_bits, keys);
    k_final<<<2, 256, 0, stream>>>(keys, flags, out);
}